// Round 8
// baseline (336.578 us; speedup 1.0000x reference)
//
#include <hip/hip_runtime.h>
#include <hip/hip_bf16.h>

#define B_ 8
#define N_ 2048
#define D_ 128

typedef __bf16 bf16_t;
typedef __bf16 v8bf __attribute__((ext_vector_type(8)));
typedef float  v4f  __attribute__((ext_vector_type(4)));

// ---------------------------------------------------------------------------
// k_prep: WT[o][i] = (bf16)Ww[i][o]; AT[o][i] = (bf16)Aw[i][o].
// ---------------------------------------------------------------------------
__global__ __launch_bounds__(256) void k_prep(
    const float* __restrict__ Ww, const float* __restrict__ Aw,
    bf16_t* __restrict__ WT, bf16_t* __restrict__ AT)
{
    int idx = blockIdx.x * 256 + threadIdx.x;   // 0..16383
    int o = idx >> 7, i = idx & 127;
    WT[idx] = (bf16_t)Ww[i * D_ + o];
    AT[idx] = (bf16_t)Aw[i * D_ + o];
}

// ---------------------------------------------------------------------------
// k_hg v2: h = x@W + b; g = h@A.  Block = 32 rows, 8 waves (512 thr):
// wave = (rg: 16-row group) x (dh: 32-col quarter).  Grid 512 -> 16 waves/CU
// (old version had 1 wave/SIMD chip-wide: zero latency hiding).
// ---------------------------------------------------------------------------
__global__ __launch_bounds__(512) void k_hg(
    const float* __restrict__ x, const float* __restrict__ Wb,
    const bf16_t* __restrict__ WT, const bf16_t* __restrict__ AT,
    bf16_t* __restrict__ hb, bf16_t* __restrict__ gb)
{
    int tid = threadIdx.x;
    int lane = tid & 63;
    int wave = tid >> 6;
    int q = lane >> 4;
    int c = lane & 15;
    int rg = wave & 1;            // row-group
    int dh = wave >> 1;           // d-quarter (2 ct tiles)
    int row0 = blockIdx.x * 32;   // flat row base (b*N+n)
    int nrow = row0 + rg * 16;

    __shared__ float hs[32][132];

    // A-frags from x (fp32 -> bf16)
    v8bf ax[4];
#pragma unroll
    for (int kc = 0; kc < 4; ++kc) {
        const float* src = x + (size_t)(nrow + c) * D_ + kc * 32 + q * 8;
        float4 f0 = *(const float4*)src;
        float4 f1 = *(const float4*)(src + 4);
        v8bf a;
        a[0]=(bf16_t)f0.x; a[1]=(bf16_t)f0.y; a[2]=(bf16_t)f0.z; a[3]=(bf16_t)f0.w;
        a[4]=(bf16_t)f1.x; a[5]=(bf16_t)f1.y; a[6]=(bf16_t)f1.z; a[7]=(bf16_t)f1.w;
        ax[kc] = a;
    }

    // h-GEMM: this wave's 2 ct tiles
#pragma unroll
    for (int t = 0; t < 2; ++t) {
        int ct = dh * 2 + t;
        float bias = Wb[ct * 16 + c];
        v4f acc = {bias, bias, bias, bias};
#pragma unroll
        for (int kc = 0; kc < 4; ++kc) {
            v8bf bw = *(const v8bf*)(WT + (size_t)(ct * 16 + c) * D_ + kc * 32 + q * 8);
            acc = __builtin_amdgcn_mfma_f32_16x16x32_bf16(ax[kc], bw, acc, 0, 0, 0);
        }
#pragma unroll
        for (int r = 0; r < 4; ++r) hs[rg * 16 + q * 4 + r][ct * 16 + c] = acc[r];
    }
    __syncthreads();

    // bf16 A-frags for g-GEMM
    v8bf ahf[4];
#pragma unroll
    for (int kc = 0; kc < 4; ++kc) {
        v4f p0 = *(const v4f*)&hs[rg * 16 + c][kc * 32 + q * 8];
        v4f p1 = *(const v4f*)&hs[rg * 16 + c][kc * 32 + q * 8 + 4];
        v8bf a;
#pragma unroll
        for (int j = 0; j < 4; ++j) { a[j] = (bf16_t)p0[j]; a[j+4] = (bf16_t)p1[j]; }
        ahf[kc] = a;
    }
    // coalesced hb store
    {
        int r2 = tid >> 4, s = tid & 15;
        v4f p0 = *(const v4f*)&hs[r2][s * 8];
        v4f p1 = *(const v4f*)&hs[r2][s * 8 + 4];
        v8bf hv;
#pragma unroll
        for (int j = 0; j < 4; ++j) { hv[j] = (bf16_t)p0[j]; hv[j+4] = (bf16_t)p1[j]; }
        *(v8bf*)(hb + (size_t)(row0 + r2) * D_ + s * 8) = hv;
    }

    // g-GEMM
    v4f gacc[2];
#pragma unroll
    for (int t = 0; t < 2; ++t) {
        int ct = dh * 2 + t;
        v4f acc = {0.f, 0.f, 0.f, 0.f};
#pragma unroll
        for (int kc = 0; kc < 4; ++kc) {
            v8bf bw = *(const v8bf*)(AT + (size_t)(ct * 16 + c) * D_ + kc * 32 + q * 8);
            acc = __builtin_amdgcn_mfma_f32_16x16x32_bf16(ahf[kc], bw, acc, 0, 0, 0);
        }
        gacc[t] = acc;
    }
    __syncthreads();   // all hs reads done
#pragma unroll
    for (int t = 0; t < 2; ++t) {
        int ct = dh * 2 + t;
#pragma unroll
        for (int r = 0; r < 4; ++r) hs[rg * 16 + q * 4 + r][ct * 16 + c] = gacc[t][r];
    }
    __syncthreads();
    // coalesced gb store
    {
        int r2 = tid >> 4, s = tid & 15;
        v4f p0 = *(const v4f*)&hs[r2][s * 8];
        v4f p1 = *(const v4f*)&hs[r2][s * 8 + 4];
        v8bf gv;
#pragma unroll
        for (int j = 0; j < 4; ++j) { gv[j] = (bf16_t)p0[j]; gv[j+4] = (bf16_t)p1[j]; }
        *(v8bf*)(gb + (size_t)(row0 + r2) * D_ + s * 8) = gv;
    }
}

// ---------------------------------------------------------------------------
// k_att v6: LDS-staged A-operand GEMM.  E = G_n H_m^T + H_n G_m^T;
// P~ = (adj>0)*exp(E) -> bf16 Pt + colsum, all fused in C-layout.
// grid 2048: b(8,=bid&7) x nblk(32, 64 n-rows) x mgrp(8, 256 m-cols); 4 waves.
// Block stages h/g n-tile in LDS (34 KB, padded rows); each wave owns a 64-m
// span; per 16-m tile: 8 global B-loads (dbuf) + 32 ds_read_b128 -> 32 MFMAs.
// No big persistent register state -> no remat, no spills.
// ---------------------------------------------------------------------------
__global__ __launch_bounds__(256, 3) void k_att(
    const bf16_t* __restrict__ hb, const bf16_t* __restrict__ gb,
    const float* __restrict__ adj, float* __restrict__ colsum,
    bf16_t* __restrict__ Pt)
{
    int bid = blockIdx.x;
    int b = bid & 7;
    int rest = bid >> 3;          // 0..255
    int nblk = rest >> 3;         // 0..31
    int mgrp = rest & 7;          // 0..7
    int tid = threadIdx.x;
    int wave = tid >> 6;
    int lane = tid & 63;
    int q = lane >> 4;
    int c = lane & 15;
    int nbase = nblk * 64;
    int mwav = mgrp * 256 + wave * 64;
    const size_t hgoff = (size_t)b * N_ * D_;
    const float* adjb = adj + (size_t)b * N_ * N_;

    __shared__ __align__(16) bf16_t hs[64][136];   // +8 pad
    __shared__ __align__(16) bf16_t gs[64][136];

    // cooperative staging of the 64-row n-tile
    {
        int r = tid >> 2, seg = tid & 3;
        const bf16_t* hsrc = hb + hgoff + (size_t)(nbase + r) * D_ + seg * 32;
        const bf16_t* gsrc = gb + hgoff + (size_t)(nbase + r) * D_ + seg * 32;
#pragma unroll
        for (int v = 0; v < 4; ++v) {
            *(v8bf*)&hs[r][seg * 32 + v * 8] = *(const v8bf*)(hsrc + v * 8);
            *(v8bf*)&gs[r][seg * 32 + v * 8] = *(const v8bf*)(gsrc + v * 8);
        }
    }
    __syncthreads();

    // B-frag register double buffer
    v8bf bh[4], bg[4], bhn[4], bgn[4];
#pragma unroll
    for (int kc = 0; kc < 4; ++kc) {
        size_t off = hgoff + (size_t)(mwav + c) * D_ + kc * 32 + q * 8;
        bh[kc] = *(const v8bf*)(hb + off);
        bg[kc] = *(const v8bf*)(gb + off);
    }

    for (int t = 0; t < 4; ++t) {
        int mt = mwav + t * 16;
        // adj tile (C-layout aligned: 16 lanes x 4B = one 64B line per row)
        float av[4][4];
#pragma unroll
        for (int sub = 0; sub < 4; ++sub)
#pragma unroll
            for (int r = 0; r < 4; ++r)
                av[sub][r] = adjb[(size_t)(nbase + sub * 16 + q * 4 + r) * N_ + mt + c];
        // prefetch next-t B-frags
        if (t < 3) {
#pragma unroll
            for (int kc = 0; kc < 4; ++kc) {
                size_t off = hgoff + (size_t)(mt + 16 + c) * D_ + kc * 32 + q * 8;
                bhn[kc] = *(const v8bf*)(hb + off);
                bgn[kc] = *(const v8bf*)(gb + off);
            }
        }
        // E tiles: A from LDS, 32 MFMAs (4 independent chains)
        v4f e[4];
#pragma unroll
        for (int sub = 0; sub < 4; ++sub) e[sub] = (v4f){0.f, 0.f, 0.f, 0.f};
#pragma unroll
        for (int kc = 0; kc < 4; ++kc)
#pragma unroll
            for (int sub = 0; sub < 4; ++sub) {
                v8bf ag = *(const v8bf*)&gs[sub * 16 + c][kc * 32 + q * 8];
                v8bf ah = *(const v8bf*)&hs[sub * 16 + c][kc * 32 + q * 8];
                e[sub] = __builtin_amdgcn_mfma_f32_16x16x32_bf16(ag, bh[kc], e[sub], 0, 0, 0);
                e[sub] = __builtin_amdgcn_mfma_f32_16x16x32_bf16(ah, bg[kc], e[sub], 0, 0, 0);
            }
        // fused mask + exp + colsum + Pt store (C-layout)
        float cs = 0.f;
#pragma unroll
        for (int sub = 0; sub < 4; ++sub)
#pragma unroll
            for (int r = 0; r < 4; ++r) {
                float ex = __expf(e[sub][r]);
                float pv = (av[sub][r] > 0.f) ? ex : 0.f;
                cs += pv;
                Pt[((size_t)b * N_ + nbase + sub * 16 + q * 4 + r) * N_ + mt + c] = (bf16_t)pv;
            }
        cs += __shfl_xor(cs, 16);
        cs += __shfl_xor(cs, 32);
        if (lane < 16) atomicAdd(&colsum[b * N_ + mt + lane], cs);
#pragma unroll
        for (int kc = 0; kc < 4; ++kc) { bh[kc] = bhn[kc]; bg[kc] = bgn[kc]; }
    }
}

// ---------------------------------------------------------------------------
// k_scaleT: hbTs[b][d][m] = h[b][m][d] * inv(colsum[b][m]).
// ---------------------------------------------------------------------------
__global__ __launch_bounds__(256) void k_scaleT(
    const bf16_t* __restrict__ hb, const float* __restrict__ colsum,
    bf16_t* __restrict__ hbTs)
{
    int bid = blockIdx.x;
    int b = bid >> 6;
    int rem = bid & 63;
    int nblk = rem >> 1;
    int dblk = rem & 1;
    int tid = threadIdx.x;
    __shared__ bf16_t sm[64][72];
    __shared__ float sinv[64];
    int n0 = nblk * 64, d0 = dblk * 64;
    int r = tid >> 3, cg = tid & 7;
#pragma unroll
    for (int rr = 0; rr < 2; ++rr) {
        int row = r + rr * 32;
        *(v8bf*)&sm[row][cg * 8] =
            *(const v8bf*)(hb + (size_t)(b * N_ + n0 + row) * D_ + d0 + cg * 8);
    }
    if (tid < 64) {
        float s = colsum[b * N_ + n0 + tid];
        sinv[tid] = (s > 0.f) ? 1.f / s : 0.f;
    }
    __syncthreads();
#pragma unroll
    for (int rr = 0; rr < 2; ++rr) {
        int dr = r + rr * 32;
        v8bf v;
#pragma unroll
        for (int jj = 0; jj < 8; ++jj)
            v[jj] = (bf16_t)((float)sm[cg * 8 + jj][dr] * sinv[cg * 8 + jj]);
        *(v8bf*)(hbTs + (size_t)(b * D_ + d0 + dr) * N_ + n0 + cg * 8) = v;
    }
}

// ---------------------------------------------------------------------------
// k_out: h_prime = Pt @ hbTs, fused relu+gate+output epilogue.
// grid 512 (b=bid&7, 32-row n-tiles), 512 thr = 8 waves; wave = m-octant
// covering 32 n x 128 d (acc = 2 sub x 8 dt = 64 regs).
// ---------------------------------------------------------------------------
__global__ __launch_bounds__(512, 4) void k_out(
    const bf16_t* __restrict__ Pt, const bf16_t* __restrict__ hbTs,
    const float* __restrict__ x, const float* __restrict__ gw,
    const float* __restrict__ gbias, float* __restrict__ out)
{
    int bid = blockIdx.x;
    int b = bid & 7;
    int nblk = bid >> 3;          // 0..63
    int tid = threadIdx.x;
    int wave = tid >> 6;          // m-octant
    int lane = tid & 63;
    int q = lane >> 4;
    int c = lane & 15;
    int nbase = nblk * 32;
    int m0 = wave * 256;

    __shared__ float hp[32][132];

    const bf16_t* hTb = hbTs + (size_t)b * D_ * N_;
    const bf16_t* Pb  = Pt + (size_t)b * N_ * N_;

    v4f acc[2][8];
#pragma unroll
    for (int sub = 0; sub < 2; ++sub)
#pragma unroll
        for (int dt = 0; dt < 8; ++dt) acc[sub][dt] = (v4f){0.f, 0.f, 0.f, 0.f};

    for (int ch = 0; ch < 8; ++ch) {
        int mch = m0 + ch * 32;
        v8bf a[2];
#pragma unroll
        for (int sub = 0; sub < 2; ++sub)
            a[sub] = *(const v8bf*)(Pb + (size_t)(nbase + sub * 16 + c) * N_ + mch + q * 8);
        v8bf vt[8];
#pragma unroll
        for (int dt = 0; dt < 8; ++dt)
            vt[dt] = *(const v8bf*)(hTb + (size_t)(dt * 16 + c) * N_ + mch + q * 8);
#pragma unroll
        for (int dt = 0; dt < 8; ++dt)
#pragma unroll
            for (int sub = 0; sub < 2; ++sub)
                acc[sub][dt] = __builtin_amdgcn_mfma_f32_16x16x32_bf16(a[sub], vt[dt], acc[sub][dt], 0, 0, 0);
    }

    // combine the 8 m-octants in LDS
    if (wave == 0) {
#pragma unroll
        for (int sub = 0; sub < 2; ++sub)
#pragma unroll
            for (int dt = 0; dt < 8; ++dt)
#pragma unroll
                for (int r = 0; r < 4; ++r)
                    hp[sub * 16 + q * 4 + r][dt * 16 + c] = acc[sub][dt][r];
    }
    __syncthreads();
#pragma unroll
    for (int wv = 1; wv < 8; ++wv) {
        if (wave == wv) {
#pragma unroll
            for (int sub = 0; sub < 2; ++sub)
#pragma unroll
                for (int dt = 0; dt < 8; ++dt)
#pragma unroll
                    for (int r = 0; r < 4; ++r)
                        hp[sub * 16 + q * 4 + r][dt * 16 + c] += acc[sub][dt][r];
        }
        __syncthreads();
    }

    // fused epilogue: 512 thr = 32 rows x 16 segs x 8 d
    int row = tid >> 4;
    int seg = tid & 15;
    size_t g = (size_t)b * N_ + nbase + row;
    const float* xr = x + g * D_ + seg * 8;
    float4 xa = *(const float4*)xr;
    float4 xb = *(const float4*)(xr + 4);
    float hv[8];
#pragma unroll
    for (int j = 0; j < 8; ++j) hv[j] = fmaxf(hp[row][seg * 8 + j], 0.f);
    float part = xa.x * gw[seg*8+0] + xa.y * gw[seg*8+1] + xa.z * gw[seg*8+2] + xa.w * gw[seg*8+3]
               + xb.x * gw[seg*8+4] + xb.y * gw[seg*8+5] + xb.z * gw[seg*8+6] + xb.w * gw[seg*8+7];
#pragma unroll
    for (int j = 0; j < 8; ++j) part += hv[j] * gw[D_ + seg * 8 + j];
    part += __shfl_xor(part, 1);
    part += __shfl_xor(part, 2);
    part += __shfl_xor(part, 4);
    part += __shfl_xor(part, 8);
    float coeff = 1.f / (1.f + __expf(-(part + gbias[0])));
    float4 o0, o1;
    o0.x = coeff * xa.x + (1.f - coeff) * hv[0];
    o0.y = coeff * xa.y + (1.f - coeff) * hv[1];
    o0.z = coeff * xa.z + (1.f - coeff) * hv[2];
    o0.w = coeff * xa.w + (1.f - coeff) * hv[3];
    o1.x = coeff * xb.x + (1.f - coeff) * hv[4];
    o1.y = coeff * xb.y + (1.f - coeff) * hv[5];
    o1.z = coeff * xb.z + (1.f - coeff) * hv[6];
    o1.w = coeff * xb.w + (1.f - coeff) * hv[7];
    float* orow = out + g * D_ + seg * 8;
    *(float4*)orow = o0;
    *(float4*)(orow + 4) = o1;
}

// ---------------------------------------------------------------------------
extern "C" void kernel_launch(void* const* d_in, const int* in_sizes, int n_in,
                              void* d_out, int out_size, void* d_ws, size_t ws_size,
                              hipStream_t stream)
{
    const float* x     = (const float*)d_in[0];
    const float* adj   = (const float*)d_in[1];
    const float* Ww    = (const float*)d_in[2];
    const float* Wb    = (const float*)d_in[3];
    const float* Aw    = (const float*)d_in[4];
    const float* gw    = (const float*)d_in[5];
    const float* gbias = (const float*)d_in[6];
    float* out = (float*)d_out;

    char* ws = (char*)d_ws;
    bf16_t* hb     = (bf16_t*)(ws);                          // 4 MB
    bf16_t* gb     = (bf16_t*)(ws + (4 << 20));              // 4 MB
    bf16_t* hbTs   = (bf16_t*)(ws + (8 << 20));              // 4 MB
    float*  colsum = (float*)(ws + (12 << 20));              // 64 KB
    bf16_t* Pt     = (bf16_t*)(ws + (17 << 20));             // 64 MB
    bf16_t* WT     = (bf16_t*)(ws + (81 << 20));             // 32 KB
    bf16_t* AT     = (bf16_t*)(ws + (81 << 20) + (32 << 10));// 32 KB

    hipMemsetAsync(colsum, 0, B_ * N_ * sizeof(float), stream);
    k_prep<<<64, 256, 0, stream>>>(Ww, Aw, WT, AT);
    k_hg<<<B_ * N_ / 32, 512, 0, stream>>>(x, Wb, WT, AT, hb, gb);
    k_att<<<2048, 256, 0, stream>>>(hb, gb, adj, colsum, Pt);
    k_scaleT<<<512, 256, 0, stream>>>(hb, colsum, hbTs);
    k_out<<<512, 512, 0, stream>>>(Pt, hbTs, x, gw, gbias, out);
}

// Round 9
// 329.726 us; speedup vs baseline: 1.0208x; 1.0208x over previous
//
#include <hip/hip_runtime.h>
#include <hip/hip_bf16.h>

#define B_ 8
#define N_ 2048
#define D_ 128

typedef __bf16 bf16_t;
typedef __bf16 v8bf __attribute__((ext_vector_type(8)));
typedef float  v4f  __attribute__((ext_vector_type(4)));

// ---------------------------------------------------------------------------
// k_prep: WT[o][i] = (bf16)Ww[i][o]; AT[o][i] = (bf16)Aw[i][o].
// ---------------------------------------------------------------------------
__global__ __launch_bounds__(256) void k_prep(
    const float* __restrict__ Ww, const float* __restrict__ Aw,
    bf16_t* __restrict__ WT, bf16_t* __restrict__ AT)
{
    int idx = blockIdx.x * 256 + threadIdx.x;   // 0..16383
    int o = idx >> 7, i = idx & 127;
    WT[idx] = (bf16_t)Ww[i * D_ + o];
    AT[idx] = (bf16_t)Aw[i * D_ + o];
}

// ---------------------------------------------------------------------------
// k_hg v2: h = x@W + b; g = h@A.  Block = 32 rows, 8 waves (512 thr):
// wave = (rg: 16-row group) x (dh: 32-col quarter).
// ---------------------------------------------------------------------------
__global__ __launch_bounds__(512) void k_hg(
    const float* __restrict__ x, const float* __restrict__ Wb,
    const bf16_t* __restrict__ WT, const bf16_t* __restrict__ AT,
    bf16_t* __restrict__ hb, bf16_t* __restrict__ gb)
{
    int tid = threadIdx.x;
    int lane = tid & 63;
    int wave = tid >> 6;
    int q = lane >> 4;
    int c = lane & 15;
    int rg = wave & 1;            // row-group
    int dh = wave >> 1;           // d-quarter (2 ct tiles)
    int row0 = blockIdx.x * 32;   // flat row base (b*N+n)
    int nrow = row0 + rg * 16;

    __shared__ float hs[32][132];

    v8bf ax[4];
#pragma unroll
    for (int kc = 0; kc < 4; ++kc) {
        const float* src = x + (size_t)(nrow + c) * D_ + kc * 32 + q * 8;
        float4 f0 = *(const float4*)src;
        float4 f1 = *(const float4*)(src + 4);
        v8bf a;
        a[0]=(bf16_t)f0.x; a[1]=(bf16_t)f0.y; a[2]=(bf16_t)f0.z; a[3]=(bf16_t)f0.w;
        a[4]=(bf16_t)f1.x; a[5]=(bf16_t)f1.y; a[6]=(bf16_t)f1.z; a[7]=(bf16_t)f1.w;
        ax[kc] = a;
    }

#pragma unroll
    for (int t = 0; t < 2; ++t) {
        int ct = dh * 2 + t;
        float bias = Wb[ct * 16 + c];
        v4f acc = {bias, bias, bias, bias};
#pragma unroll
        for (int kc = 0; kc < 4; ++kc) {
            v8bf bw = *(const v8bf*)(WT + (size_t)(ct * 16 + c) * D_ + kc * 32 + q * 8);
            acc = __builtin_amdgcn_mfma_f32_16x16x32_bf16(ax[kc], bw, acc, 0, 0, 0);
        }
#pragma unroll
        for (int r = 0; r < 4; ++r) hs[rg * 16 + q * 4 + r][ct * 16 + c] = acc[r];
    }
    __syncthreads();

    v8bf ahf[4];
#pragma unroll
    for (int kc = 0; kc < 4; ++kc) {
        v4f p0 = *(const v4f*)&hs[rg * 16 + c][kc * 32 + q * 8];
        v4f p1 = *(const v4f*)&hs[rg * 16 + c][kc * 32 + q * 8 + 4];
        v8bf a;
#pragma unroll
        for (int j = 0; j < 4; ++j) { a[j] = (bf16_t)p0[j]; a[j+4] = (bf16_t)p1[j]; }
        ahf[kc] = a;
    }
    {
        int r2 = tid >> 4, s = tid & 15;
        v4f p0 = *(const v4f*)&hs[r2][s * 8];
        v4f p1 = *(const v4f*)&hs[r2][s * 8 + 4];
        v8bf hv;
#pragma unroll
        for (int j = 0; j < 4; ++j) { hv[j] = (bf16_t)p0[j]; hv[j+4] = (bf16_t)p1[j]; }
        *(v8bf*)(hb + (size_t)(row0 + r2) * D_ + s * 8) = hv;
    }

    v4f gacc[2];
#pragma unroll
    for (int t = 0; t < 2; ++t) {
        int ct = dh * 2 + t;
        v4f acc = {0.f, 0.f, 0.f, 0.f};
#pragma unroll
        for (int kc = 0; kc < 4; ++kc) {
            v8bf bw = *(const v8bf*)(AT + (size_t)(ct * 16 + c) * D_ + kc * 32 + q * 8);
            acc = __builtin_amdgcn_mfma_f32_16x16x32_bf16(ahf[kc], bw, acc, 0, 0, 0);
        }
        gacc[t] = acc;
    }
    __syncthreads();
#pragma unroll
    for (int t = 0; t < 2; ++t) {
        int ct = dh * 2 + t;
#pragma unroll
        for (int r = 0; r < 4; ++r) hs[rg * 16 + q * 4 + r][ct * 16 + c] = gacc[t][r];
    }
    __syncthreads();
    {
        int r2 = tid >> 4, s = tid & 15;
        v4f p0 = *(const v4f*)&hs[r2][s * 8];
        v4f p1 = *(const v4f*)&hs[r2][s * 8 + 4];
        v8bf gv;
#pragma unroll
        for (int j = 0; j < 4; ++j) { gv[j] = (bf16_t)p0[j]; gv[j+4] = (bf16_t)p1[j]; }
        *(v8bf*)(gb + (size_t)(row0 + r2) * D_ + s * 8) = gv;
    }
}

// ---------------------------------------------------------------------------
// k_att v7: LDS-A GEMM + LDS pack stage.
// grid 4096: b(8,=bid&7) x nblk(64, 32 n-rows) x mgrp(8, 256 m-cols); 4 waves.
// Phase 1 (t-loop): E tiles from LDS A-tile + global B-dbuf -> unmasked
//   bf16 exp(E) into per-wave LDS slab (C-layout writes, wave-local).
// Phase 2 (pack): coalesced adj read (32B/lane), mask, colsum in regs
//   (shuffle over row-lanes), Pt written as 128B full-line stores.
// LDS 35.8 KB -> 4 blocks/CU (50% occupancy).  No big register state.
// ---------------------------------------------------------------------------
__global__ __launch_bounds__(256, 4) void k_att(
    const bf16_t* __restrict__ hb, const bf16_t* __restrict__ gb,
    const float* __restrict__ adj, float* __restrict__ colsum,
    bf16_t* __restrict__ Pt)
{
    int bid = blockIdx.x;
    int b = bid & 7;
    int rest = bid >> 3;          // 0..511
    int nblk = rest >> 3;         // 0..63 (32-row tile)
    int mgrp = rest & 7;          // 0..7  (256-col group)
    int tid = threadIdx.x;
    int wave = tid >> 6;
    int lane = tid & 63;
    int q = lane >> 4;
    int c = lane & 15;
    int nbase = nblk * 32;
    int mwav = mgrp * 256 + wave * 64;
    const size_t hgoff = (size_t)b * N_ * D_;
    const float* adjb = adj + (size_t)b * N_ * N_;

    __shared__ __align__(16) bf16_t hs[32][136];
    __shared__ __align__(16) bf16_t gs[32][136];
    __shared__ __align__(16) bf16_t eb_all[4][32][72];
    bf16_t (*eb)[72] = eb_all[wave];

    // cooperative staging of the 32-row n-tile (2 chunks per array per thread)
    {
        int r = tid >> 3;
        int ch0 = tid & 7;
#pragma unroll
        for (int cc = 0; cc < 2; ++cc) {
            int ch = ch0 + cc * 8;
            *(v8bf*)&hs[r][ch * 8] =
                *(const v8bf*)(hb + hgoff + (size_t)(nbase + r) * D_ + ch * 8);
            *(v8bf*)&gs[r][ch * 8] =
                *(const v8bf*)(gb + hgoff + (size_t)(nbase + r) * D_ + ch * 8);
        }
    }
    __syncthreads();

    // B-frag register double buffer
    v8bf bh[4], bg[4], bhn[4], bgn[4];
#pragma unroll
    for (int kc = 0; kc < 4; ++kc) {
        size_t off = hgoff + (size_t)(mwav + c) * D_ + kc * 32 + q * 8;
        bh[kc] = *(const v8bf*)(hb + off);
        bg[kc] = *(const v8bf*)(gb + off);
    }

    for (int t = 0; t < 4; ++t) {
        if (t < 3) {
            int mt = mwav + (t + 1) * 16;
#pragma unroll
            for (int kc = 0; kc < 4; ++kc) {
                size_t off = hgoff + (size_t)(mt + c) * D_ + kc * 32 + q * 8;
                bhn[kc] = *(const v8bf*)(hb + off);
                bgn[kc] = *(const v8bf*)(gb + off);
            }
        }
        v4f e[2];
        e[0] = (v4f){0.f, 0.f, 0.f, 0.f};
        e[1] = (v4f){0.f, 0.f, 0.f, 0.f};
#pragma unroll
        for (int kc = 0; kc < 4; ++kc)
#pragma unroll
            for (int sub = 0; sub < 2; ++sub) {
                v8bf ag = *(const v8bf*)&gs[sub * 16 + c][kc * 32 + q * 8];
                v8bf ah = *(const v8bf*)&hs[sub * 16 + c][kc * 32 + q * 8];
                e[sub] = __builtin_amdgcn_mfma_f32_16x16x32_bf16(ag, bh[kc], e[sub], 0, 0, 0);
                e[sub] = __builtin_amdgcn_mfma_f32_16x16x32_bf16(ah, bg[kc], e[sub], 0, 0, 0);
            }
        // unmasked exp -> per-wave LDS slab (wave-local, no block barrier)
#pragma unroll
        for (int sub = 0; sub < 2; ++sub)
#pragma unroll
            for (int r = 0; r < 4; ++r)
                eb[sub * 16 + q * 4 + r][t * 16 + c] = (bf16_t)__expf(e[sub][r]);
#pragma unroll
        for (int kc = 0; kc < 4; ++kc) { bh[kc] = bhn[kc]; bg[kc] = bgn[kc]; }
    }
    __builtin_amdgcn_wave_barrier();

    // Pack stage: coalesced adj, mask, colsum, full-line Pt stores.
    int prow = lane >> 3, pseg = lane & 7;   // 8 rows x 8 m-segs of 8
    float cs[8];
#pragma unroll
    for (int j = 0; j < 8; ++j) cs[j] = 0.f;
#pragma unroll
    for (int pass = 0; pass < 4; ++pass) {
        int row = pass * 8 + prow;
        v8bf e8 = *(const v8bf*)&eb[row][pseg * 8];
        const float* ap = adjb + (size_t)(nbase + row) * N_ + mwav + pseg * 8;
        float4 a0 = *(const float4*)ap;
        float4 a1 = *(const float4*)(ap + 4);
        float am[8] = {a0.x, a0.y, a0.z, a0.w, a1.x, a1.y, a1.z, a1.w};
        v8bf o;
#pragma unroll
        for (int j = 0; j < 8; ++j) {
            bool live = am[j] > 0.f;
            o[j] = live ? e8[j] : (bf16_t)0.f;
            cs[j] += live ? (float)e8[j] : 0.f;
        }
        *(v8bf*)(Pt + ((size_t)b * N_ + nbase + row) * N_ + mwav + pseg * 8) = o;
    }
#pragma unroll
    for (int j = 0; j < 8; ++j) {
        cs[j] += __shfl_xor(cs[j], 8);
        cs[j] += __shfl_xor(cs[j], 16);
        cs[j] += __shfl_xor(cs[j], 32);
    }
    if (lane < 8) {
#pragma unroll
        for (int j = 0; j < 8; ++j)
            atomicAdd(&colsum[b * N_ + mwav + lane * 8 + j], cs[j]);
    }
}

// ---------------------------------------------------------------------------
// k_scaleT: hbTs[b][d][m] = h[b][m][d] * inv(colsum[b][m]).
// ---------------------------------------------------------------------------
__global__ __launch_bounds__(256) void k_scaleT(
    const bf16_t* __restrict__ hb, const float* __restrict__ colsum,
    bf16_t* __restrict__ hbTs)
{
    int bid = blockIdx.x;
    int b = bid >> 6;
    int rem = bid & 63;
    int nblk = rem >> 1;
    int dblk = rem & 1;
    int tid = threadIdx.x;
    __shared__ bf16_t sm[64][72];
    __shared__ float sinv[64];
    int n0 = nblk * 64, d0 = dblk * 64;
    int r = tid >> 3, cg = tid & 7;
#pragma unroll
    for (int rr = 0; rr < 2; ++rr) {
        int row = r + rr * 32;
        *(v8bf*)&sm[row][cg * 8] =
            *(const v8bf*)(hb + (size_t)(b * N_ + n0 + row) * D_ + d0 + cg * 8);
    }
    if (tid < 64) {
        float s = colsum[b * N_ + n0 + tid];
        sinv[tid] = (s > 0.f) ? 1.f / s : 0.f;
    }
    __syncthreads();
#pragma unroll
    for (int rr = 0; rr < 2; ++rr) {
        int dr = r + rr * 32;
        v8bf v;
#pragma unroll
        for (int jj = 0; jj < 8; ++jj)
            v[jj] = (bf16_t)((float)sm[cg * 8 + jj][dr] * sinv[cg * 8 + jj]);
        *(v8bf*)(hbTs + (size_t)(b * D_ + d0 + dr) * N_ + n0 + cg * 8) = v;
    }
}

// ---------------------------------------------------------------------------
// k_out: h_prime = Pt @ hbTs, fused relu+gate+output epilogue.
// grid 512 (b=bid&7, 32-row n-tiles), 512 thr = 8 waves; wave = m-octant
// covering 32 n x 128 d (acc = 2 sub x 8 dt = 64 regs).
// ---------------------------------------------------------------------------
__global__ __launch_bounds__(512, 4) void k_out(
    const bf16_t* __restrict__ Pt, const bf16_t* __restrict__ hbTs,
    const float* __restrict__ x, const float* __restrict__ gw,
    const float* __restrict__ gbias, float* __restrict__ out)
{
    int bid = blockIdx.x;
    int b = bid & 7;
    int nblk = bid >> 3;          // 0..63
    int tid = threadIdx.x;
    int wave = tid >> 6;          // m-octant
    int lane = tid & 63;
    int q = lane >> 4;
    int c = lane & 15;
    int nbase = nblk * 32;
    int m0 = wave * 256;

    __shared__ float hp[32][132];

    const bf16_t* hTb = hbTs + (size_t)b * D_ * N_;
    const bf16_t* Pb  = Pt + (size_t)b * N_ * N_;

    v4f acc[2][8];
#pragma unroll
    for (int sub = 0; sub < 2; ++sub)
#pragma unroll
        for (int dt = 0; dt < 8; ++dt) acc[sub][dt] = (v4f){0.f, 0.f, 0.f, 0.f};

    for (int ch = 0; ch < 8; ++ch) {
        int mch = m0 + ch * 32;
        v8bf a[2];
#pragma unroll
        for (int sub = 0; sub < 2; ++sub)
            a[sub] = *(const v8bf*)(Pb + (size_t)(nbase + sub * 16 + c) * N_ + mch + q * 8);
        v8bf vt[8];
#pragma unroll
        for (int dt = 0; dt < 8; ++dt)
            vt[dt] = *(const v8bf*)(hTb + (size_t)(dt * 16 + c) * N_ + mch + q * 8);
#pragma unroll
        for (int dt = 0; dt < 8; ++dt)
#pragma unroll
            for (int sub = 0; sub < 2; ++sub)
                acc[sub][dt] = __builtin_amdgcn_mfma_f32_16x16x32_bf16(a[sub], vt[dt], acc[sub][dt], 0, 0, 0);
    }

    if (wave == 0) {
#pragma unroll
        for (int sub = 0; sub < 2; ++sub)
#pragma unroll
            for (int dt = 0; dt < 8; ++dt)
#pragma unroll
                for (int r = 0; r < 4; ++r)
                    hp[sub * 16 + q * 4 + r][dt * 16 + c] = acc[sub][dt][r];
    }
    __syncthreads();
#pragma unroll
    for (int wv = 1; wv < 8; ++wv) {
        if (wave == wv) {
#pragma unroll
            for (int sub = 0; sub < 2; ++sub)
#pragma unroll
                for (int dt = 0; dt < 8; ++dt)
#pragma unroll
                    for (int r = 0; r < 4; ++r)
                        hp[sub * 16 + q * 4 + r][dt * 16 + c] += acc[sub][dt][r];
        }
        __syncthreads();
    }

    int row = tid >> 4;
    int seg = tid & 15;
    size_t g = (size_t)b * N_ + nbase + row;
    const float* xr = x + g * D_ + seg * 8;
    float4 xa = *(const float4*)xr;
    float4 xb = *(const float4*)(xr + 4);
    float hv[8];
#pragma unroll
    for (int j = 0; j < 8; ++j) hv[j] = fmaxf(hp[row][seg * 8 + j], 0.f);
    float part = xa.x * gw[seg*8+0] + xa.y * gw[seg*8+1] + xa.z * gw[seg*8+2] + xa.w * gw[seg*8+3]
               + xb.x * gw[seg*8+4] + xb.y * gw[seg*8+5] + xb.z * gw[seg*8+6] + xb.w * gw[seg*8+7];
#pragma unroll
    for (int j = 0; j < 8; ++j) part += hv[j] * gw[D_ + seg * 8 + j];
    part += __shfl_xor(part, 1);
    part += __shfl_xor(part, 2);
    part += __shfl_xor(part, 4);
    part += __shfl_xor(part, 8);
    float coeff = 1.f / (1.f + __expf(-(part + gbias[0])));
    float4 o0, o1;
    o0.x = coeff * xa.x + (1.f - coeff) * hv[0];
    o0.y = coeff * xa.y + (1.f - coeff) * hv[1];
    o0.z = coeff * xa.z + (1.f - coeff) * hv[2];
    o0.w = coeff * xa.w + (1.f - coeff) * hv[3];
    o1.x = coeff * xb.x + (1.f - coeff) * hv[4];
    o1.y = coeff * xb.y + (1.f - coeff) * hv[5];
    o1.z = coeff * xb.z + (1.f - coeff) * hv[6];
    o1.w = coeff * xb.w + (1.f - coeff) * hv[7];
    float* orow = out + g * D_ + seg * 8;
    *(float4*)orow = o0;
    *(float4*)(orow + 4) = o1;
}

// ---------------------------------------------------------------------------
extern "C" void kernel_launch(void* const* d_in, const int* in_sizes, int n_in,
                              void* d_out, int out_size, void* d_ws, size_t ws_size,
                              hipStream_t stream)
{
    const float* x     = (const float*)d_in[0];
    const float* adj   = (const float*)d_in[1];
    const float* Ww    = (const float*)d_in[2];
    const float* Wb    = (const float*)d_in[3];
    const float* Aw    = (const float*)d_in[4];
    const float* gw    = (const float*)d_in[5];
    const float* gbias = (const float*)d_in[6];
    float* out = (float*)d_out;

    char* ws = (char*)d_ws;
    bf16_t* hb     = (bf16_t*)(ws);                          // 4 MB
    bf16_t* gb     = (bf16_t*)(ws + (4 << 20));              // 4 MB
    bf16_t* hbTs   = (bf16_t*)(ws + (8 << 20));              // 4 MB
    float*  colsum = (float*)(ws + (12 << 20));              // 64 KB
    bf16_t* Pt     = (bf16_t*)(ws + (17 << 20));             // 64 MB
    bf16_t* WT     = (bf16_t*)(ws + (81 << 20));             // 32 KB
    bf16_t* AT     = (bf16_t*)(ws + (81 << 20) + (32 << 10));// 32 KB

    hipMemsetAsync(colsum, 0, B_ * N_ * sizeof(float), stream);
    k_prep<<<64, 256, 0, stream>>>(Ww, Aw, WT, AT);
    k_hg<<<B_ * N_ / 32, 512, 0, stream>>>(x, Wb, WT, AT, hb, gb);
    k_att<<<4096, 256, 0, stream>>>(hb, gb, adj, colsum, Pt);
    k_scaleT<<<512, 256, 0, stream>>>(hb, colsum, hbTs);
    k_out<<<512, 512, 0, stream>>>(Pt, hbTs, x, gw, gbias, out);
}

// Round 10
// 325.965 us; speedup vs baseline: 1.0326x; 1.0115x over previous
//
#include <hip/hip_runtime.h>
#include <hip/hip_bf16.h>

#define B_ 8
#define N_ 2048
#define D_ 128

typedef __bf16 bf16_t;
typedef __bf16 v8bf __attribute__((ext_vector_type(8)));
typedef float  v4f  __attribute__((ext_vector_type(4)));

// ---------------------------------------------------------------------------
// k_prep: WT[o][i] = (bf16)Ww[i][o]; AT[o][i] = (bf16)Aw[i][o].
// ---------------------------------------------------------------------------
__global__ __launch_bounds__(256) void k_prep(
    const float* __restrict__ Ww, const float* __restrict__ Aw,
    bf16_t* __restrict__ WT, bf16_t* __restrict__ AT)
{
    int idx = blockIdx.x * 256 + threadIdx.x;   // 0..16383
    int o = idx >> 7, i = idx & 127;
    WT[idx] = (bf16_t)Ww[i * D_ + o];
    AT[idx] = (bf16_t)Aw[i * D_ + o];
}

// ---------------------------------------------------------------------------
// k_hg v2: h = x@W + b; g = h@A.  Block = 32 rows, 8 waves (512 thr).
// ---------------------------------------------------------------------------
__global__ __launch_bounds__(512) void k_hg(
    const float* __restrict__ x, const float* __restrict__ Wb,
    const bf16_t* __restrict__ WT, const bf16_t* __restrict__ AT,
    bf16_t* __restrict__ hb, bf16_t* __restrict__ gb)
{
    int tid = threadIdx.x;
    int lane = tid & 63;
    int wave = tid >> 6;
    int q = lane >> 4;
    int c = lane & 15;
    int rg = wave & 1;            // row-group
    int dh = wave >> 1;           // d-quarter (2 ct tiles)
    int row0 = blockIdx.x * 32;   // flat row base (b*N+n)
    int nrow = row0 + rg * 16;

    __shared__ float hs[32][132];

    v8bf ax[4];
#pragma unroll
    for (int kc = 0; kc < 4; ++kc) {
        const float* src = x + (size_t)(nrow + c) * D_ + kc * 32 + q * 8;
        float4 f0 = *(const float4*)src;
        float4 f1 = *(const float4*)(src + 4);
        v8bf a;
        a[0]=(bf16_t)f0.x; a[1]=(bf16_t)f0.y; a[2]=(bf16_t)f0.z; a[3]=(bf16_t)f0.w;
        a[4]=(bf16_t)f1.x; a[5]=(bf16_t)f1.y; a[6]=(bf16_t)f1.z; a[7]=(bf16_t)f1.w;
        ax[kc] = a;
    }

#pragma unroll
    for (int t = 0; t < 2; ++t) {
        int ct = dh * 2 + t;
        float bias = Wb[ct * 16 + c];
        v4f acc = {bias, bias, bias, bias};
#pragma unroll
        for (int kc = 0; kc < 4; ++kc) {
            v8bf bw = *(const v8bf*)(WT + (size_t)(ct * 16 + c) * D_ + kc * 32 + q * 8);
            acc = __builtin_amdgcn_mfma_f32_16x16x32_bf16(ax[kc], bw, acc, 0, 0, 0);
        }
#pragma unroll
        for (int r = 0; r < 4; ++r) hs[rg * 16 + q * 4 + r][ct * 16 + c] = acc[r];
    }
    __syncthreads();

    v8bf ahf[4];
#pragma unroll
    for (int kc = 0; kc < 4; ++kc) {
        v4f p0 = *(const v4f*)&hs[rg * 16 + c][kc * 32 + q * 8];
        v4f p1 = *(const v4f*)&hs[rg * 16 + c][kc * 32 + q * 8 + 4];
        v8bf a;
#pragma unroll
        for (int j = 0; j < 4; ++j) { a[j] = (bf16_t)p0[j]; a[j+4] = (bf16_t)p1[j]; }
        ahf[kc] = a;
    }
    {
        int r2 = tid >> 4, s = tid & 15;
        v4f p0 = *(const v4f*)&hs[r2][s * 8];
        v4f p1 = *(const v4f*)&hs[r2][s * 8 + 4];
        v8bf hv;
#pragma unroll
        for (int j = 0; j < 4; ++j) { hv[j] = (bf16_t)p0[j]; hv[j+4] = (bf16_t)p1[j]; }
        *(v8bf*)(hb + (size_t)(row0 + r2) * D_ + s * 8) = hv;
    }

    v4f gacc[2];
#pragma unroll
    for (int t = 0; t < 2; ++t) {
        int ct = dh * 2 + t;
        v4f acc = {0.f, 0.f, 0.f, 0.f};
#pragma unroll
        for (int kc = 0; kc < 4; ++kc) {
            v8bf bw = *(const v8bf*)(AT + (size_t)(ct * 16 + c) * D_ + kc * 32 + q * 8);
            acc = __builtin_amdgcn_mfma_f32_16x16x32_bf16(ahf[kc], bw, acc, 0, 0, 0);
        }
        gacc[t] = acc;
    }
    __syncthreads();
#pragma unroll
    for (int t = 0; t < 2; ++t) {
        int ct = dh * 2 + t;
#pragma unroll
        for (int r = 0; r < 4; ++r) hs[rg * 16 + q * 4 + r][ct * 16 + c] = gacc[t][r];
    }
    __syncthreads();
    {
        int r2 = tid >> 4, s = tid & 15;
        v4f p0 = *(const v4f*)&hs[r2][s * 8];
        v4f p1 = *(const v4f*)&hs[r2][s * 8 + 4];
        v8bf gv;
#pragma unroll
        for (int j = 0; j < 4; ++j) { gv[j] = (bf16_t)p0[j]; gv[j+4] = (bf16_t)p1[j]; }
        *(v8bf*)(gb + (size_t)(row0 + r2) * D_ + s * 8) = gv;
    }
}

// ---------------------------------------------------------------------------
// k_att v8: LDS-A GEMM + LDS pack stage.  NO ATOMICS: colsum partials are
// written as coalesced plain stores to csp[b][nblk][m] (4 MB), reduced by
// k_inv.  Everything else identical to v7 (clean causal experiment).
// grid 4096: b(8,=bid&7) x nblk(64, 32 n-rows) x mgrp(8, 256 m-cols); 4 waves.
// ---------------------------------------------------------------------------
__global__ __launch_bounds__(256, 4) void k_att(
    const bf16_t* __restrict__ hb, const bf16_t* __restrict__ gb,
    const float* __restrict__ adj, float* __restrict__ csp,
    bf16_t* __restrict__ Pt)
{
    int bid = blockIdx.x;
    int b = bid & 7;
    int rest = bid >> 3;          // 0..511
    int nblk = rest >> 3;         // 0..63 (32-row tile)
    int mgrp = rest & 7;          // 0..7  (256-col group)
    int tid = threadIdx.x;
    int wave = tid >> 6;
    int lane = tid & 63;
    int q = lane >> 4;
    int c = lane & 15;
    int nbase = nblk * 32;
    int mwav = mgrp * 256 + wave * 64;
    const size_t hgoff = (size_t)b * N_ * D_;
    const float* adjb = adj + (size_t)b * N_ * N_;

    __shared__ __align__(16) bf16_t hs[32][136];
    __shared__ __align__(16) bf16_t gs[32][136];
    __shared__ __align__(16) bf16_t eb_all[4][32][72];
    bf16_t (*eb)[72] = eb_all[wave];

    // cooperative staging of the 32-row n-tile
    {
        int r = tid >> 3;
        int ch0 = tid & 7;
#pragma unroll
        for (int cc = 0; cc < 2; ++cc) {
            int ch = ch0 + cc * 8;
            *(v8bf*)&hs[r][ch * 8] =
                *(const v8bf*)(hb + hgoff + (size_t)(nbase + r) * D_ + ch * 8);
            *(v8bf*)&gs[r][ch * 8] =
                *(const v8bf*)(gb + hgoff + (size_t)(nbase + r) * D_ + ch * 8);
        }
    }
    __syncthreads();

    // B-frag register double buffer
    v8bf bh[4], bg[4], bhn[4], bgn[4];
#pragma unroll
    for (int kc = 0; kc < 4; ++kc) {
        size_t off = hgoff + (size_t)(mwav + c) * D_ + kc * 32 + q * 8;
        bh[kc] = *(const v8bf*)(hb + off);
        bg[kc] = *(const v8bf*)(gb + off);
    }

    for (int t = 0; t < 4; ++t) {
        if (t < 3) {
            int mt = mwav + (t + 1) * 16;
#pragma unroll
            for (int kc = 0; kc < 4; ++kc) {
                size_t off = hgoff + (size_t)(mt + c) * D_ + kc * 32 + q * 8;
                bhn[kc] = *(const v8bf*)(hb + off);
                bgn[kc] = *(const v8bf*)(gb + off);
            }
        }
        v4f e[2];
        e[0] = (v4f){0.f, 0.f, 0.f, 0.f};
        e[1] = (v4f){0.f, 0.f, 0.f, 0.f};
#pragma unroll
        for (int kc = 0; kc < 4; ++kc)
#pragma unroll
            for (int sub = 0; sub < 2; ++sub) {
                v8bf ag = *(const v8bf*)&gs[sub * 16 + c][kc * 32 + q * 8];
                v8bf ah = *(const v8bf*)&hs[sub * 16 + c][kc * 32 + q * 8];
                e[sub] = __builtin_amdgcn_mfma_f32_16x16x32_bf16(ag, bh[kc], e[sub], 0, 0, 0);
                e[sub] = __builtin_amdgcn_mfma_f32_16x16x32_bf16(ah, bg[kc], e[sub], 0, 0, 0);
            }
#pragma unroll
        for (int sub = 0; sub < 2; ++sub)
#pragma unroll
            for (int r = 0; r < 4; ++r)
                eb[sub * 16 + q * 4 + r][t * 16 + c] = (bf16_t)__expf(e[sub][r]);
#pragma unroll
        for (int kc = 0; kc < 4; ++kc) { bh[kc] = bhn[kc]; bg[kc] = bgn[kc]; }
    }
    __builtin_amdgcn_wave_barrier();

    // Pack stage: coalesced adj, mask, colsum partials, full-line Pt stores.
    int prow = lane >> 3, pseg = lane & 7;   // 8 rows x 8 m-segs of 8
    float cs[8];
#pragma unroll
    for (int j = 0; j < 8; ++j) cs[j] = 0.f;
#pragma unroll
    for (int pass = 0; pass < 4; ++pass) {
        int row = pass * 8 + prow;
        v8bf e8 = *(const v8bf*)&eb[row][pseg * 8];
        const float* ap = adjb + (size_t)(nbase + row) * N_ + mwav + pseg * 8;
        float4 a0 = *(const float4*)ap;
        float4 a1 = *(const float4*)(ap + 4);
        float am[8] = {a0.x, a0.y, a0.z, a0.w, a1.x, a1.y, a1.z, a1.w};
        v8bf o;
#pragma unroll
        for (int j = 0; j < 8; ++j) {
            bool live = am[j] > 0.f;
            o[j] = live ? e8[j] : (bf16_t)0.f;
            cs[j] += live ? (float)e8[j] : 0.f;
        }
        *(v8bf*)(Pt + ((size_t)b * N_ + nbase + row) * N_ + mwav + pseg * 8) = o;
    }
    // reduce over prow (bits 3..5); all lanes with same pseg end identical
#pragma unroll
    for (int j = 0; j < 8; ++j) {
        cs[j] += __shfl_xor(cs[j], 8);
        cs[j] += __shfl_xor(cs[j], 16);
        cs[j] += __shfl_xor(cs[j], 32);
    }
    // coalesced partial store: lanes 0..7 write 256B contiguous (no atomics)
    if (lane < 8) {
        float* dst = csp + ((size_t)(b * 64 + nblk)) * N_ + mwav + lane * 8;
        float4 s0 = {cs[0], cs[1], cs[2], cs[3]};
        float4 s1 = {cs[4], cs[5], cs[6], cs[7]};
        *(float4*)dst = s0;
        *(float4*)(dst + 4) = s1;
    }
}

// ---------------------------------------------------------------------------
// k_inv: inv[b][m] = 1 / sum_k csp[b][k][m]  (0 if dead column).
// ---------------------------------------------------------------------------
__global__ __launch_bounds__(256) void k_inv(
    const float* __restrict__ csp, float* __restrict__ inv)
{
    int idx = blockIdx.x * 256 + threadIdx.x;   // b*2048 + m
    int b = idx >> 11, m = idx & 2047;
    const float* p = csp + ((size_t)b * 64) * N_ + m;
    float s = 0.f;
#pragma unroll 8
    for (int k = 0; k < 64; ++k) s += p[(size_t)k * N_];
    inv[idx] = (s > 0.f) ? 1.f / s : 0.f;
}

// ---------------------------------------------------------------------------
// k_scaleT: hbTs[b][d][m] = h[b][m][d] * inv[b][m].
// ---------------------------------------------------------------------------
__global__ __launch_bounds__(256) void k_scaleT(
    const bf16_t* __restrict__ hb, const float* __restrict__ inv,
    bf16_t* __restrict__ hbTs)
{
    int bid = blockIdx.x;
    int b = bid >> 6;
    int rem = bid & 63;
    int nblk = rem >> 1;
    int dblk = rem & 1;
    int tid = threadIdx.x;
    __shared__ bf16_t sm[64][72];
    __shared__ float sinv[64];
    int n0 = nblk * 64, d0 = dblk * 64;
    int r = tid >> 3, cg = tid & 7;
#pragma unroll
    for (int rr = 0; rr < 2; ++rr) {
        int row = r + rr * 32;
        *(v8bf*)&sm[row][cg * 8] =
            *(const v8bf*)(hb + (size_t)(b * N_ + n0 + row) * D_ + d0 + cg * 8);
    }
    if (tid < 64) sinv[tid] = inv[b * N_ + n0 + tid];
    __syncthreads();
#pragma unroll
    for (int rr = 0; rr < 2; ++rr) {
        int dr = r + rr * 32;
        v8bf v;
#pragma unroll
        for (int jj = 0; jj < 8; ++jj)
            v[jj] = (bf16_t)((float)sm[cg * 8 + jj][dr] * sinv[cg * 8 + jj]);
        *(v8bf*)(hbTs + (size_t)(b * D_ + d0 + dr) * N_ + n0 + cg * 8) = v;
    }
}

// ---------------------------------------------------------------------------
// k_out: h_prime = Pt @ hbTs, fused relu+gate+output epilogue.
// grid 512 (b=bid&7, 32-row n-tiles), 512 thr = 8 waves; wave = m-octant
// covering 32 n x 128 d (acc = 2 sub x 8 dt = 64 regs).
// ---------------------------------------------------------------------------
__global__ __launch_bounds__(512, 4) void k_out(
    const bf16_t* __restrict__ Pt, const bf16_t* __restrict__ hbTs,
    const float* __restrict__ x, const float* __restrict__ gw,
    const float* __restrict__ gbias, float* __restrict__ out)
{
    int bid = blockIdx.x;
    int b = bid & 7;
    int nblk = bid >> 3;          // 0..63
    int tid = threadIdx.x;
    int wave = tid >> 6;          // m-octant
    int lane = tid & 63;
    int q = lane >> 4;
    int c = lane & 15;
    int nbase = nblk * 32;
    int m0 = wave * 256;

    __shared__ float hp[32][132];

    const bf16_t* hTb = hbTs + (size_t)b * D_ * N_;
    const bf16_t* Pb  = Pt + (size_t)b * N_ * N_;

    v4f acc[2][8];
#pragma unroll
    for (int sub = 0; sub < 2; ++sub)
#pragma unroll
        for (int dt = 0; dt < 8; ++dt) acc[sub][dt] = (v4f){0.f, 0.f, 0.f, 0.f};

    for (int ch = 0; ch < 8; ++ch) {
        int mch = m0 + ch * 32;
        v8bf a[2];
#pragma unroll
        for (int sub = 0; sub < 2; ++sub)
            a[sub] = *(const v8bf*)(Pb + (size_t)(nbase + sub * 16 + c) * N_ + mch + q * 8);
        v8bf vt[8];
#pragma unroll
        for (int dt = 0; dt < 8; ++dt)
            vt[dt] = *(const v8bf*)(hTb + (size_t)(dt * 16 + c) * N_ + mch + q * 8);
#pragma unroll
        for (int dt = 0; dt < 8; ++dt)
#pragma unroll
            for (int sub = 0; sub < 2; ++sub)
                acc[sub][dt] = __builtin_amdgcn_mfma_f32_16x16x32_bf16(a[sub], vt[dt], acc[sub][dt], 0, 0, 0);
    }

    if (wave == 0) {
#pragma unroll
        for (int sub = 0; sub < 2; ++sub)
#pragma unroll
            for (int dt = 0; dt < 8; ++dt)
#pragma unroll
                for (int r = 0; r < 4; ++r)
                    hp[sub * 16 + q * 4 + r][dt * 16 + c] = acc[sub][dt][r];
    }
    __syncthreads();
#pragma unroll
    for (int wv = 1; wv < 8; ++wv) {
        if (wave == wv) {
#pragma unroll
            for (int sub = 0; sub < 2; ++sub)
#pragma unroll
                for (int dt = 0; dt < 8; ++dt)
#pragma unroll
                    for (int r = 0; r < 4; ++r)
                        hp[sub * 16 + q * 4 + r][dt * 16 + c] += acc[sub][dt][r];
        }
        __syncthreads();
    }

    int row = tid >> 4;
    int seg = tid & 15;
    size_t g = (size_t)b * N_ + nbase + row;
    const float* xr = x + g * D_ + seg * 8;
    float4 xa = *(const float4*)xr;
    float4 xb = *(const float4*)(xr + 4);
    float hv[8];
#pragma unroll
    for (int j = 0; j < 8; ++j) hv[j] = fmaxf(hp[row][seg * 8 + j], 0.f);
    float part = xa.x * gw[seg*8+0] + xa.y * gw[seg*8+1] + xa.z * gw[seg*8+2] + xa.w * gw[seg*8+3]
               + xb.x * gw[seg*8+4] + xb.y * gw[seg*8+5] + xb.z * gw[seg*8+6] + xb.w * gw[seg*8+7];
#pragma unroll
    for (int j = 0; j < 8; ++j) part += hv[j] * gw[D_ + seg * 8 + j];
    part += __shfl_xor(part, 1);
    part += __shfl_xor(part, 2);
    part += __shfl_xor(part, 4);
    part += __shfl_xor(part, 8);
    float coeff = 1.f / (1.f + __expf(-(part + gbias[0])));
    float4 o0, o1;
    o0.x = coeff * xa.x + (1.f - coeff) * hv[0];
    o0.y = coeff * xa.y + (1.f - coeff) * hv[1];
    o0.z = coeff * xa.z + (1.f - coeff) * hv[2];
    o0.w = coeff * xa.w + (1.f - coeff) * hv[3];
    o1.x = coeff * xb.x + (1.f - coeff) * hv[4];
    o1.y = coeff * xb.y + (1.f - coeff) * hv[5];
    o1.z = coeff * xb.z + (1.f - coeff) * hv[6];
    o1.w = coeff * xb.w + (1.f - coeff) * hv[7];
    float* orow = out + g * D_ + seg * 8;
    *(float4*)orow = o0;
    *(float4*)(orow + 4) = o1;
}

// ---------------------------------------------------------------------------
extern "C" void kernel_launch(void* const* d_in, const int* in_sizes, int n_in,
                              void* d_out, int out_size, void* d_ws, size_t ws_size,
                              hipStream_t stream)
{
    const float* x     = (const float*)d_in[0];
    const float* adj   = (const float*)d_in[1];
    const float* Ww    = (const float*)d_in[2];
    const float* Wb    = (const float*)d_in[3];
    const float* Aw    = (const float*)d_in[4];
    const float* gw    = (const float*)d_in[5];
    const float* gbias = (const float*)d_in[6];
    float* out = (float*)d_out;

    char* ws = (char*)d_ws;
    bf16_t* hb     = (bf16_t*)(ws);                          // 4 MB
    bf16_t* gb     = (bf16_t*)(ws + (4 << 20));              // 4 MB
    bf16_t* hbTs   = (bf16_t*)(ws + (8 << 20));              // 4 MB
    float*  csp    = (float*)(ws + (12 << 20));              // 4 MB partials
    float*  inv    = (float*)(ws + (16 << 20));              // 64 KB
    bf16_t* Pt     = (bf16_t*)(ws + (17 << 20));             // 64 MB
    bf16_t* WT     = (bf16_t*)(ws + (81 << 20));             // 32 KB
    bf16_t* AT     = (bf16_t*)(ws + (81 << 20) + (32 << 10));// 32 KB

    k_prep<<<64, 256, 0, stream>>>(Ww, Aw, WT, AT);
    k_hg<<<B_ * N_ / 32, 512, 0, stream>>>(x, Wb, WT, AT, hb, gb);
    k_att<<<4096, 256, 0, stream>>>(hb, gb, adj, csp, Pt);
    k_inv<<<B_ * N_ / 256, 256, 0, stream>>>(csp, inv);
    k_scaleT<<<512, 256, 0, stream>>>(hb, inv, hbTs);
    k_out<<<512, 512, 0, stream>>>(Pt, hbTs, x, gw, gbias, out);
}